// Round 8
// baseline (1803.488 us; speedup 1.0000x reference)
//
#include <hip/hip_runtime.h>

// ---------------------------------------------------------------------------
// StyleDecorator, round 20: r19 + single-buffered LDS for TILE=128 modes.
// r19 S0 anatomy: LDS 23.5us + MFMA 7.7us + mem ~20us per CU but wall 78us
// -- components SUM (per K-step ~4800cyc vs max-resource ~1600) because only
// 2 blocks/CU (64KB dbuf LDS) leaves no TLP to cover the barrier+vmcnt(0)
// drain. Fix: DBUF=false for S0/WHITEN/COLOR -> 32KB LDS -> 4 blocks/CU
// (16 waves), trading intra-block prefetch for 4-way inter-block overlap
// (m114: waves co-schedule MFMA/mem freely). launch_bounds(256,4) caps
// VGPR at 128 (current 104). Math bit-identical. COVP (already occ-4) and
// NS (launch-bound) keep dbuf.
// ---------------------------------------------------------------------------

#define CH    512
#define NPIX  4096      // 64*64
#define HPAD  66
#define PPAD  4356      // 66*66
#define MROWS 4480      // padded row count for whitened-feature matrices
#define S0W   4480      // merged S0T width (full padded grid, 128-aligned)
#define NS_ITERS 7

typedef unsigned short u16;
typedef _Float16 half8 __attribute__((ext_vector_type(8)));
typedef __attribute__((ext_vector_type(4))) float f32x4;    // MFMA C/D

__device__ __forceinline__ float f16tof(u16 h){
  union { u16 u; _Float16 f; } v; v.u = h; return (float)v.f;
}
// x ~= h + l*2^-11, with l ~ 0.5|x| (never denormal). err ~ 2^-24|x|.
__device__ __forceinline__ void split2(float x, u16& h, u16& l){
  _Float16 hf = (_Float16)x;
  float r = (x - (float)hf) * 2048.0f;
  union { u16 u; _Float16 f; } hv, lv;
  hv.f = hf; lv.f = (_Float16)r;
  h = hv.u; l = lv.u;
}
__device__ __forceinline__ void gll16(const void* g, void* l){
  __builtin_amdgcn_global_load_lds((const __attribute__((address_space(1))) unsigned*)g,
                                   (__attribute__((address_space(3))) unsigned*)l,
                                   16, 0, 0);
}
__device__ __forceinline__ f32x4 mfma_f16(half8 a, half8 b, f32x4 c){
  return __builtin_amdgcn_mfma_f32_16x16x32_f16(a, b, c, 0, 0, 0);
}

// ---------------------------------------------------------------------------
enum { M_COVP = 0, M_NST = 1, M_X3 = 2, M_WHITEN = 3, M_S0 = 4, M_COLOR = 5 };

struct GP {
  const u16 *Ah, *Al, *Bh, *Bl;
  const u16 *Eh, *El, *Fh, *Fl;   // alt A/B for M_X3 z>=4
  size_t sAz, sBz;           // per-z strides (elements)
  float* Cf;
  u16 *Ch, *Cl;
  u16 *Gh, *Gl;              // alt C for M_X3 z>=4
  size_t sCz;
  const float* scales;
  const float* meanv;
  int K;                     // row stride (elements)
  int Kit;                   // K iteration length for this launch
};

// C[m][n] = sum_k A[m][k]*B[n][k], A,B as [row][K] fp16x2 (h, l*2^11).
// 256 threads = 4 waves; TILE in {64,128}; wave computes (TILE/2)^2.
// K-loop: DBUF ? double-buffered 1-barrier : single-buffered 2-barrier.
template<int TILE, int MODE, int KSTEP = 32, bool DBUF = true, int OCC = 2>
__global__ __launch_bounds__(256, OCC)
void gemm_sp(GP p){
  constexpr int MF = TILE / 32;
  constexpr int SLOTS = KSTEP / 8;        // 16B slots per row
  constexpr int TSUB = KSTEP / 32;        // 32-k sub-steps per K-step
  constexpr int NBUF = DBUF ? 2 : 1;
  constexpr bool SYM = (MODE == M_NST) || (MODE == M_X3);
  int z = blockIdx.z;
  int m0, n0;
  int kbase = 0;
  int za = z, zout = z;
  bool mirror = false;
  if constexpr (MODE == M_COVP){
    // XCD-pinned (matrix,k-chunk): grid 1024 1D; xcd = b%8 owns 2 pairs.
    const int b = blockIdx.x;
    const int xcd = b & 7, w = b >> 3;          // w: 0..127
    const int zc = xcd*2 + (w & 1);             // (matrix,chunk) pair 0..15
    const int tile = w >> 1;                    // 0..63
    m0 = (tile >> 3)*64; n0 = (tile & 7)*64;
    kbase = (zc & 3) * p.Kit;
    za = zc >> 2; zout = zc;
  } else if constexpr (SYM){
    int bx = blockIdx.x;
    int ty = 0;
    while((ty+1)*(ty+2)/2 <= bx) ++ty;
    int tx = bx - ty*(ty+1)/2;
    m0 = ty*64; n0 = tx*64; mirror = (tx != ty);
  } else if constexpr (MODE == M_S0){
    // 35x35 square tiles, balanced+local XCD walk: in n-group g (7 n-tiles),
    // xcd x owns m-tiles m%8 == (x+3g)%8. Per-XCD totals 154 (x=3: 147).
    const int b = blockIdx.x;                  // grid 1232 = 8*154
    const int x = b & 7;
    int rem = b >> 3;                          // 0..153
    int g = 0, R = 0, mo = 0;
    for(; g < 5; ++g){
      mo = (x + 3*g) & 7;
      R = (mo < 3) ? 5 : 4;
      if(rem < R*7) break;
      rem -= R*7;
    }
    if(g == 5) return;
    const int mi = rem / 7, ni = rem % 7;
    m0 = (mo + mi*8) * 128;
    n0 = (g*7 + ni) * 128;
  } else if constexpr (MODE == M_WHITEN){
    // XCD z-pinned: z = xcd/2; per XCD 16 m-tiles x 4 n-tiles, n innermost
    // so B(=Z, 1MB) stays L2-resident while A streams once.
    const int b = blockIdx.x;                  // grid 512 = 8*64
    const int x = b & 7, w = b >> 3;           // w: 0..63
    z = x >> 1;
    const int mt = (x & 1) + (w >> 2) * 2;     // 0..31
    m0 = mt * 128;
    n0 = (w & 3) * 128;
    za = z; zout = z;
  } else {
    m0 = blockIdx.y*TILE; n0 = blockIdx.x*TILE;
  }

  const u16 *Ah, *Al, *Bh, *Bl;
  if constexpr (MODE == M_X3){
    const size_t zb = (size_t)(z & 3) * CH * CH;
    if(z < 4){ Ah=p.Ah+zb; Al=p.Al+zb; Bh=p.Bh+zb; Bl=p.Bl+zb; }
    else     { Ah=p.Eh+zb; Al=p.El+zb; Bh=p.Fh+zb; Bl=p.Fl+zb; }
  } else {
    Ah = p.Ah + (size_t)za * p.sAz;
    Al = p.Al + (size_t)za * p.sAz;
    Bh = p.Bh + (size_t)za * p.sBz;
    Bl = p.Bl + (size_t)za * p.sBz;
  }

  const int tid = threadIdx.x, ln = tid & 63, wv = tid >> 6;
  const int wm = (wv >> 1) * (TILE/2), wn = (wv & 1) * (TILE/2);
  __shared__ __align__(16) u16 sAh[NBUF][TILE*KSTEP], sAl[NBUF][TILE*KSTEP];
  __shared__ __align__(16) u16 sBh[NBUF][TILE*KSTEP], sBl[NBUF][TILE*KSTEP];
  f32x4 acc1[MF][MF], acc2[MF][MF];
#pragma unroll
  for(int i=0;i<MF;++i)
#pragma unroll
    for(int j=0;j<MF;++j){ acc1[i][j] = (f32x4)0.0f; acc2[i][j] = (f32x4)0.0f; }
  const int K = p.K;

  auto stage = [&](int k0, int buf){
#pragma unroll
    for(int s = tid; s < TILE*SLOTS; s += 256){  // 16B slots, SLOTS per row
      const int row = s / SLOTS, pos = s % SLOTS;
      const int kc = pos ^ ((row >> 2) & (SLOTS-1));   // XOR swizzle
      const size_t ga = (size_t)(m0 + row) * K + k0 + kc*8;
      const size_t gb = (size_t)(n0 + row) * K + k0 + kc*8;
      gll16(Ah + ga, sAh[buf] + s*8);
      gll16(Al + ga, sAl[buf] + s*8);
      gll16(Bh + gb, sBh[buf] + s*8);
      gll16(Bl + gb, sBl[buf] + s*8);
    }
  };

  auto compute = [&](int buf){
    const u16* pAh = sAh[buf]; const u16* pAl = sAl[buf];
    const u16* pBh = sBh[buf]; const u16* pBl = sBl[buf];
#pragma unroll
    for(int t = 0; t < TSUB; ++t){
      half8 ah[MF], al[MF], bh[MF], bl[MF];
#pragma unroll
      for(int i=0;i<MF;++i){
        const int ra = wm + i*16 + (ln & 15);
        const int rb = wn + i*16 + (ln & 15);
        const int pa = (t*4 + (ln >> 4)) ^ ((ra >> 2) & (SLOTS-1));
        const int pb = (t*4 + (ln >> 4)) ^ ((rb >> 2) & (SLOTS-1));
        const int ofa = ra*KSTEP + pa*8;
        const int ofb = rb*KSTEP + pb*8;
        ah[i] = *(const half8*)(pAh + ofa);
        al[i] = *(const half8*)(pAl + ofa);
        bh[i] = *(const half8*)(pBh + ofb);
        bl[i] = *(const half8*)(pBl + ofb);
      }
#pragma unroll
      for(int i=0;i<MF;++i)
#pragma unroll
        for(int j=0;j<MF;++j){
          acc1[i][j] = mfma_f16(ah[i], bh[j], acc1[i][j]);
          acc2[i][j] = mfma_f16(ah[i], bl[j], acc2[i][j]);
          acc2[i][j] = mfma_f16(al[i], bh[j], acc2[i][j]);
        }
    }
  };

  if constexpr (DBUF){
    stage(kbase, 0);
    int cur = 0;
    for(int kk = 0; kk < p.Kit; kk += KSTEP){
      __syncthreads();                 // drains prefetch issued last iter
      if(kk + KSTEP < p.Kit) stage(kbase + kk + KSTEP, cur ^ 1);
      compute(cur);
      cur ^= 1;
    }
  } else {
    for(int kk = 0; kk < p.Kit; kk += KSTEP){
      stage(kbase + kk, 0);
      __syncthreads();                 // drain stage (vmcnt(0) at barrier)
      compute(0);
      __syncthreads();                 // all reads done before next overwrite
    }
  }
  // epilogue: C/D layout col=lane&15, row=(lane>>4)*4+reg
  u16 *C0 = nullptr, *C1 = nullptr;
  if constexpr (MODE == M_NST){
    const size_t zb = (size_t)z * p.sCz;
    C0 = p.Ch + zb; C1 = p.Cl + zb;
  } else if constexpr (MODE == M_X3){
    const size_t zb = (size_t)(z & 3) * p.sCz;
    if(z < 4){ C0 = p.Ch + zb; C1 = p.Cl + zb; }
    else     { C0 = p.Gh + zb; C1 = p.Gl + zb; }
  }
#pragma unroll
  for(int i=0;i<MF;++i)
#pragma unroll
    for(int j=0;j<MF;++j)
#pragma unroll
      for(int r=0;r<4;++r){
        const int m = m0 + wm + i*16 + (ln >> 4)*4 + r;
        const int n = n0 + wn + j*16 + (ln & 15);
        float v = acc1[i][j][r] + acc2[i][j][r] * (1.0f/2048.0f);
        if constexpr (MODE == M_COVP){
          p.Cf[(size_t)zout * p.sCz + (size_t)m * CH + n] = v;   // raw partial
        } else if constexpr (MODE == M_NST || MODE == M_X3){
          if constexpr (MODE == M_NST) v = -0.5f*v + ((m == n) ? 1.5f : 0.0f);
          u16 h, l; split2(v, h, l);
          C0[(size_t)m*CH + n] = h; C1[(size_t)m*CH + n] = l;
          if(mirror){
            C0[(size_t)n*CH + m] = h; C1[(size_t)n*CH + m] = l;
          }
        } else if constexpr (MODE == M_WHITEN){
          v *= p.scales[z*4 + 3];                 // rsqrt(c)
          const int prow = ((m >> 6) + 1)*HPAD + (m & 63) + 1;
          u16 h, l; split2(v, h, l);
          const size_t o = (size_t)z*p.sCz + (size_t)prow*CH + n;
          p.Ch[o] = h; p.Cl[o] = l;
        } else if constexpr (MODE == M_S0){
          p.Cf[(size_t)m * S0W + n] = v;
        } else {                                  // M_COLOR
          const float sc = p.scales[(2+z)*4 + 2]; // sqrt(c)
          const float mu = p.meanv[(2+z)*CH + m];
          p.Cf[(size_t)z*p.sCz + (size_t)m*NPIX + n] = v*sc + mu;
        }
      }
}

// ------- cov reduce: sum 4 K-chunks, scale 1/4095; fused |row| sums ---------
// Block covers 256 consecutive elements = half a row -> one atomicAdd/block.
__global__ __launch_bounds__(256)
void cov_reduce_kernel(const float* __restrict__ covp, float* __restrict__ cov,
                       float* __restrict__ rowsum){
  size_t t = (size_t)blockIdx.x * 256 + threadIdx.x;   // 4*512*512
  int z = (int)(t >> 18);
  size_t e = t & 262143;
  float s = 0.f;
#pragma unroll
  for(int c = 0; c < 4; ++c) s += covp[((size_t)(z*4 + c) << 18) + e];
  s *= (1.0f / 4095.0f);
  cov[t] = s;
  __shared__ float red[256];
  red[threadIdx.x] = fabsf(s); __syncthreads();
  for(int w = 128; w > 0; w >>= 1){
    if(threadIdx.x < w) red[threadIdx.x] += red[threadIdx.x + w];
    __syncthreads();
  }
  if(threadIdx.x == 0){
    int row = (int)(e >> 9);
    atomicAdd(&rowsum[z*512 + row], red[0]);
  }
}

__global__ __launch_bounds__(256)
void scale_fin_kernel(const float* __restrict__ rowsum, float* __restrict__ scales){
  __shared__ float red[256];
  for(int z = 0; z < 4; ++z){
    float m = fmaxf(rowsum[z*512 + threadIdx.x], rowsum[z*512 + 256 + threadIdx.x]);
    red[threadIdx.x] = m; __syncthreads();
    for(int w = 128; w > 0; w >>= 1){
      if(threadIdx.x < w) red[threadIdx.x] = fmaxf(red[threadIdx.x], red[threadIdx.x + w]);
      __syncthreads();
    }
    if(threadIdx.x == 0){
      float c = red[0];
      scales[z*4+0] = c;
      scales[z*4+1] = 1.0f / c;
      scales[z*4+2] = sqrtf(c);
      scales[z*4+3] = rsqrtf(c);
    }
    __syncthreads();
  }
}

// ---------------- per-(matrix,channel) mean over 4096 pixels ----------------
__global__ __launch_bounds__(256)
void mean_kernel(const float* __restrict__ content, const float* __restrict__ style,
                 float* __restrict__ meanv){
  int mm = blockIdx.x;           // 0..2047
  int z = mm >> 9, c = mm & 511;
  const float* X = ((z < 2) ? content + (size_t)z * CH * NPIX
                            : style   + (size_t)(z - 2) * CH * NPIX) + (size_t)c * NPIX;
  float s = 0.f;
  for(int i = threadIdx.x; i < NPIX; i += 256) s += X[i];
  __shared__ float red[256];
  red[threadIdx.x] = s; __syncthreads();
  for(int w = 128; w > 0; w >>= 1){
    if(threadIdx.x < w) red[threadIdx.x] += red[threadIdx.x + w];
    __syncthreads();
  }
  if(threadIdx.x == 0) meanv[mm] = red[0] * (1.0f / NPIX);
}

// ------- center + fp16x2 split, emit both [c][pix] and [pix][c] layouts -----
__global__ __launch_bounds__(256)
void center_split_kernel(const float* __restrict__ content, const float* __restrict__ style,
                         const float* __restrict__ meanv,
                         u16* __restrict__ Xch, u16* __restrict__ Xcl,
                         u16* __restrict__ XcTh, u16* __restrict__ XcTl){
  int z = blockIdx.z;
  const float* X = (z < 2) ? content + (size_t)z * CH * NPIX
                           : style   + (size_t)(z - 2) * CH * NPIX;
  int p0 = blockIdx.x * 64, c0 = blockIdx.y * 64;
  __shared__ float T[64][65];
  int col = threadIdx.x & 63, rq = threadIdx.x >> 6;
#pragma unroll
  for(int i = 0; i < 16; ++i){
    int r = i*4 + rq;
    int c = c0 + r;
    float v = X[(size_t)c * NPIX + p0 + col] - meanv[z*CH + c];
    u16 h, l; split2(v, h, l);
    size_t o = (size_t)(z*CH + c) * NPIX + p0 + col;
    Xch[o] = h; Xcl[o] = l;
    T[col][r] = v;
  }
  __syncthreads();
#pragma unroll
  for(int i = 0; i < 16; ++i){
    int r = i*4 + rq;                 // pixel-in-tile
    float v = T[r][col];
    u16 h, l; split2(v, h, l);
    size_t o = (size_t)(z*NPIX + p0 + r) * CH + c0 + col;
    XcTh[o] = h; XcTl[o] = l;
  }
}

// ---------------- Y0 = cov/c (x2), Z0 = I (x2) ------------------------------
__global__ __launch_bounds__(256)
void ns_init_kernel(const float* __restrict__ cov, const float* __restrict__ scales,
                    u16* Yh, u16* Yl, u16* Zh, u16* Zl){
  size_t t = (size_t)blockIdx.x * 256 + threadIdx.x;   // 4*512*512
  int z = (int)(t >> 18);
  size_t e = t & 262143;
  int row = (int)(e >> 9), col = (int)(e & 511);
  float v = cov[t] * scales[z*4+1];
  u16 h, l; split2(v, h, l);
  Yh[t] = h; Yl[t] = l;
  Zh[t] = (row == col) ? (u16)0x3C00 : (u16)0;   // fp16 1.0
  Zl[t] = 0;
}

// ---------------- cn2[p'] = ||whitened style column||^2 ---------------------
__global__ __launch_bounds__(256)
void cn2_kernel(const u16* __restrict__ Wh, const u16* __restrict__ Wl,
                float* __restrict__ cn2){
  int b = blockIdx.y;
  int row = blockIdx.x * 16 + (threadIdx.x >> 4);
  int t = threadIdx.x & 15;
  float s = 0.f;
  if(row < PPAD){
    size_t base = ((size_t)(2 + b) * MROWS + row) * CH;
    for(int ch = t; ch < 64; ch += 16){
      uint4 hv = *(const uint4*)(Wh + base + ch*8);
      uint4 lv = *(const uint4*)(Wl + base + ch*8);
      const unsigned* hw = (const unsigned*)&hv;
      const unsigned* lw = (const unsigned*)&lv;
#pragma unroll
      for(int w = 0; w < 4; ++w){
        float v0 = f16tof((u16)(hw[w] & 0xFFFF)) + f16tof((u16)(lw[w] & 0xFFFF))*(1.0f/2048.0f);
        float v1 = f16tof((u16)(hw[w] >> 16))    + f16tof((u16)(lw[w] >> 16))*(1.0f/2048.0f);
        s = fmaf(v0, v0, s); s = fmaf(v1, v1, s);
      }
    }
  }
  for(int off = 8; off; off >>= 1) s += __shfl_down(s, off, 16);
  if(t == 0 && row < PPAD) cn2[b*PPAD + row] = s;
}

// ---------------- rnorm[p] = 1/(sqrt(sum of 9 taps)+1e-5) -------------------
__global__ __launch_bounds__(256)
void rnorm_kernel(const float* __restrict__ cn2, float* __restrict__ rnorm){
  int b = blockIdx.y;
  int p = blockIdx.x * 256 + threadIdx.x;   // 0..4095
  int py = p >> 6, px = p & 63;
  const float* c2 = cn2 + (size_t)b * PPAD + (size_t)py * HPAD + px;
  float s = 0.f;
#pragma unroll
  for(int i = 0; i < 3; ++i)
#pragma unroll
    for(int j = 0; j < 3; ++j) s += c2[i * HPAD + j];
  rnorm[b * 4096 + p] = 1.0f / (sqrtf(s) + 1e-5f);
}

// ---------------- per-p-chunk argmax of 9-tap stencil score (fused) ---------
// XCD-pinned p-slices; 2 q-streams per thread; result via packed u64
// atomicMax: key = (ordered_f32(score) << 32) | (0xFFFFFFFF - p).
// Exactly reproduces first-max (lowest-p) selection of a serial scan.
__device__ __forceinline__ unsigned long long score_key(float s, int p){
  unsigned u = __float_as_uint(s);
  u = (u & 0x80000000u) ? ~u : (u | 0x80000000u);
  return ((unsigned long long)u << 32) | (unsigned long long)(0xFFFFFFFFu - (unsigned)p);
}

__global__ __launch_bounds__(256)
void score_partial_kernel(const float* __restrict__ S0T, const float* __restrict__ rnorm,
                          unsigned long long* __restrict__ skey, int b){
  const int blk = blockIdx.x;                // grid 512
  const int xcd = blk & 7, w = blk >> 3;     // w: 0..63
  const int chunk = xcd*8 + (w & 7);
  const int qg = w >> 3;                     // 0..7
  const int t = threadIdx.x;
  const int q0 = qg*512 + t, q1 = q0 + 256;
  const int qc0 = (q0 >> 6)*HPAD + (q0 & 63);
  const int qc1 = (q1 >> 6)*HPAD + (q1 & 63);
  const float* rn = rnorm + b * 4096;
  float b0 = -1e30f, b1 = -1e30f; int i0 = 0, i1 = 0;
  for(int p = chunk*64; p < chunk*64 + 64; ++p){
    const size_t base = (size_t)((p >> 6)*HPAD + (p & 63)) * S0W;
    float s0 = 0.f, s1 = 0.f;
#pragma unroll
    for(int i = 0; i < 3; ++i)
#pragma unroll
      for(int j = 0; j < 3; ++j){
        const size_t d = (size_t)(i*HPAD + j) * (S0W + 1);
        s0 += S0T[base + qc0 + d];
        s1 += S0T[base + qc1 + d];
      }
    const float r = rn[p];
    s0 *= r; s1 *= r;
    if(s0 > b0){ b0 = s0; i0 = p; }
    if(s1 > b1){ b1 = s1; i1 = p; }
  }
  atomicMax(skey + (size_t)b*4096 + q0, score_key(b0, i0));
  atomicMax(skey + (size_t)b*4096 + q1, score_key(b1, i1));
}

// ---------------- gather matched patches, overlap-add, write RT x2 ----------
__global__ __launch_bounds__(256)
void gather_kernel(const u16* __restrict__ Wh, const u16* __restrict__ Wl,
                   const unsigned long long* __restrict__ skey,
                   u16* __restrict__ RTh, u16* __restrict__ RTl){
  int g = blockIdx.x * 256 + threadIdx.x;   // 2*4096*64
  int cg = g & 63;
  int pix = (g >> 6) & 4095;
  int b = g >> 18;
  int y = pix >> 6, x = pix & 63;
  const unsigned long long* kb = skey + (size_t)b * 4096;
  size_t matbase = (size_t)(2 + b) * MROWS * CH;
  float a8[8] = {0,0,0,0,0,0,0,0};
  int cnt = 0;
#pragma unroll
  for(int i = 0; i < 3; ++i){
    int qy = y + 1 - i;
    if((unsigned)qy >= 64u) continue;
#pragma unroll
    for(int j = 0; j < 3; ++j){
      int qx = x + 1 - j;
      if((unsigned)qx >= 64u) continue;
      int p = (int)(0xFFFFFFFFu - (unsigned)(kb[qy * 64 + qx] & 0xFFFFFFFFull));
      int row = ((p >> 6) + i) * HPAD + (p & 63) + j;
      size_t off = matbase + (size_t)row * CH + cg * 8;
      uint4 hv = *(const uint4*)(Wh + off);
      uint4 lv = *(const uint4*)(Wl + off);
      const unsigned* hw = (const unsigned*)&hv;
      const unsigned* lw = (const unsigned*)&lv;
#pragma unroll
      for(int w = 0; w < 4; ++w){
        a8[2*w]   += f16tof((u16)(hw[w] & 0xFFFF)) + f16tof((u16)(lw[w] & 0xFFFF))*(1.0f/2048.0f);
        a8[2*w+1] += f16tof((u16)(hw[w] >> 16))    + f16tof((u16)(lw[w] >> 16))*(1.0f/2048.0f);
      }
      ++cnt;
    }
  }
  float inv = 1.0f / (float)cnt;
  u16 oh[8], ol[8];
#pragma unroll
  for(int k = 0; k < 8; ++k){
    float v = a8[k] * inv;
    split2(v, oh[k], ol[k]);
  }
  size_t ro = ((size_t)(b * 4096 + pix)) * CH + cg * 8;
  *(uint4*)(RTh + ro) = *(const uint4*)oh;
  *(uint4*)(RTl + ro) = *(const uint4*)ol;
}

// ---------------------------------------------------------------------------
extern "C" void kernel_launch(void* const* d_in, const int* in_sizes, int n_in,
                              void* d_out, int out_size, void* d_ws, size_t ws_size,
                              hipStream_t stream){
  (void)in_sizes; (void)n_in; (void)out_size; (void)ws_size;
  const float* content = (const float*)d_in[0];
  const float* style   = (const float*)d_in[1];
  float* out = (float*)d_out;

  char* base = (char*)d_ws;
  size_t off = 0;
  auto take = [&](size_t nbytes) -> char* {
    char* p = base + off;
    off = (off + nbytes + 255) & ~(size_t)255;
    return p;
  };
  const size_t MAT = (size_t)CH*CH*2;            // 512x512 fp16 bytes
  const size_t FEAT = (size_t)CH*NPIX*2;         // 512x4096 fp16 bytes
  const size_t WMAT = (size_t)MROWS*CH*2;        // 4480x512 fp16 bytes
  const size_t S0SZ = (size_t)MROWS*S0W*4;       // 80.3 MB merged S0T

  float* meanv  = (float*)take((size_t)4*CH*sizeof(float));
  float* scales = (float*)take(256);
  float* rowsum = (float*)take((size_t)4*CH*sizeof(float));  // memset to 0
  float* cov    = (float*)take((size_t)4*CH*CH*sizeof(float));
  u16 *Yh=(u16*)take(4*MAT), *Yl=(u16*)take(4*MAT);
  u16 *Zh=(u16*)take(4*MAT), *Zl=(u16*)take(4*MAT);
  u16 *Th=(u16*)take(4*MAT), *Tl=(u16*)take(4*MAT);
  u16 *Ynh=(u16*)take(4*MAT), *Ynl=(u16*)take(4*MAT);
  u16 *Znh=(u16*)take(4*MAT), *Znl=(u16*)take(4*MAT);
  // cov K-split partials (16 MB) alias the NS region (dead at cov time):
  // Yh..Ynl are 8 contiguous 2MB arrays (256B-aligned takes).
  float* covp = (float*)Yh;
  // P1: Xc x2 (center->cov) then W x2 (post-NS -> end)
  char* P1 = take(2*(size_t)4*WMAT);
  u16 *Xch=(u16*)P1, *Xcl=(u16*)(P1+4*FEAT);
  u16 *Wh=(u16*)P1,  *Wl=(u16*)(P1+4*WMAT);
  // P0: XcT x2 (center->whiten), then merged S0T, then RT x2
  char* P0 = take(S0SZ);
  u16 *XcTh=(u16*)P0, *XcTl=(u16*)(P0+4*FEAT);
  float* S0T = (float*)P0;
  u16 *RTh=(u16*)P0, *RTl=(u16*)(P0+2*FEAT);
  float* cn2    = (float*)take((size_t)2*PPAD*sizeof(float));
  float* rnormb = (float*)take((size_t)2*4096*sizeof(float));
  unsigned long long* skey = (unsigned long long*)take((size_t)2*4096*8);

  hipMemsetAsync(rowsum, 0, (size_t)4*CH*sizeof(float), stream);
  hipMemsetAsync(skey, 0, (size_t)2*4096*8, stream);

  mean_kernel<<<2048, 256, 0, stream>>>(content, style, meanv);
  center_split_kernel<<<dim3(64, 8, 4), 256, 0, stream>>>(content, style, meanv,
                                                          Xch, Xcl, XcTh, XcTl);
  // cov partials: XCD-pinned (matrix,k-chunk), 1024 blocks 1D, KSTEP=32 dbuf
  // (32KB LDS -> 4 blocks/CU residency matches the 4 blocks/CU of work)
  {
    GP g{}; g.Ah=Xch; g.Al=Xcl; g.Bh=Xch; g.Bl=Xcl;
    g.sAz = g.sBz = (size_t)CH*NPIX; g.Cf = covp; g.sCz = (size_t)CH*CH;
    g.K = NPIX; g.Kit = 1024;
    gemm_sp<64, M_COVP, 32><<<dim3(1024), 256, 0, stream>>>(g);
  }
  cov_reduce_kernel<<<4096, 256, 0, stream>>>(covp, cov, rowsum);
  scale_fin_kernel<<<1, 256, 0, stream>>>(rowsum, scales);
  ns_init_kernel<<<4096, 256, 0, stream>>>(cov, scales, Yh, Yl, Zh, Zl);

  u16 *Ach[2]={Yh,Yl}, *Bch[2]={Zh,Zl}, *An[2]={Ynh,Ynl}, *Bn[2]={Znh,Znl};
  for(int it = 0; it < NS_ITERS; ++it){
    // T = 1.5I - 0.5 Z*Y  (symmetric: 36 triangle blocks, mirrored)
    GP t{}; t.Ah=Bch[0]; t.Al=Bch[1];            // Z
    t.Bh=Ach[0]; t.Bl=Ach[1];                    // Y (symmetric)
    t.sAz = t.sBz = (size_t)CH*CH; t.Ch=Th; t.Cl=Tl; t.sCz=(size_t)CH*CH;
    t.K = CH; t.Kit = CH;
    gemm_sp<64, M_NST, 64><<<dim3(36, 1, 4), 256, 0, stream>>>(t);
    // z<4: Yn = Y*T ; z>=4: Zn = T*Z  (both symmetric, mirrored)
    GP u{}; u.Ah=Ach[0]; u.Al=Ach[1];            // Y
    u.Bh=Th; u.Bl=Tl;                            // T
    u.Eh=Th; u.El=Tl;                            // T
    u.Fh=Bch[0]; u.Fl=Bch[1];                    // Z
    u.Ch=An[0]; u.Cl=An[1];
    u.Gh=Bn[0]; u.Gl=Bn[1];
    u.sCz=(size_t)CH*CH; u.K = CH; u.Kit = CH;
    gemm_sp<64, M_X3, 64><<<dim3(36, 1, 8), 256, 0, stream>>>(u);
    for(int c = 0; c < 2; ++c){ u16* tmp=Ach[c]; Ach[c]=An[c]; An[c]=tmp;
                                tmp=Bch[c]; Bch[c]=Bn[c]; Bn[c]=tmp; }
  }

  // W (padded, zero borders) -- Xc region is dead now; Wh/Wl alias it
  hipMemsetAsync(Wh, 0, 4*WMAT, stream);
  hipMemsetAsync(Wl, 0, 4*WMAT, stream);
  // W[pix][c] = XcT * Z  (Z symmetric), scaled by rsqrt(c); XCD z-pinned 1D
  {
    GP w{}; w.Ah=XcTh; w.Al=XcTl; w.sAz=(size_t)NPIX*CH;
    w.Bh=Bch[0]; w.Bl=Bch[1]; w.sBz=(size_t)CH*CH;
    w.Ch=Wh; w.Cl=Wl; w.sCz=(size_t)MROWS*CH; w.scales=scales;
    w.K = CH; w.Kit = CH;
    gemm_sp<128, M_WHITEN, 32, false, 4><<<dim3(512), 256, 0, stream>>>(w);
  }
  cn2_kernel<<<dim3(273, 2), 256, 0, stream>>>(Wh, Wl, cn2);
  rnorm_kernel<<<dim3(16, 2), 256, 0, stream>>>(cn2, rnormb);

  for(int b = 0; b < 2; ++b){
    GP s{};
    s.Ah = Wh + (size_t)(2+b)*MROWS*CH; s.Al = Wl + (size_t)(2+b)*MROWS*CH;
    s.Bh = Wh + (size_t)b*MROWS*CH;     s.Bl = Wl + (size_t)b*MROWS*CH;
    s.sAz = s.sBz = 0; s.Cf = S0T; s.sCz = 0; s.K = CH; s.Kit = CH;
    gemm_sp<128, M_S0, 32, false, 4><<<dim3(1232), 256, 0, stream>>>(s);
    score_partial_kernel<<<dim3(512), 256, 0, stream>>>(S0T, rnormb, skey, b);
  }

  gather_kernel<<<2048, 256, 0, stream>>>(Wh, Wl, skey, RTh, RTl);
  // out = Ys * R * sqrt(c) + mu   (Ys symmetric)
  {
    GP c{}; c.Ah = Ach[0] + 2*(size_t)CH*CH; c.Al = Ach[1] + 2*(size_t)CH*CH;
    c.sAz = (size_t)CH*CH;
    c.Bh = RTh; c.Bl = RTl; c.sBz = (size_t)NPIX*CH;
    c.Cf = out; c.sCz = (size_t)CH*NPIX; c.scales = scales; c.meanv = meanv;
    c.K = CH; c.Kit = CH;
    gemm_sp<128, M_COLOR, 32, false, 4><<<dim3(32, 4, 2), 256, 0, stream>>>(c);
  }
}

// Round 9
// 717.452 us; speedup vs baseline: 2.5137x; 2.5137x over previous
//
#include <hip/hip_runtime.h>

// ---------------------------------------------------------------------------
// StyleDecorator, round 21: VERBATIM revert to r19 (728.9us, session best).
// r20 post-mortem: single-buffer + launch_bounds(256,4) forced the unified
// VGPR/AGPR budget to ~128 regs while the 64x64 wave tile needs ~232
// (128 acc + ~104 arch) -> allocator clamped VGPR to 64 and SPILLED the
// accumulators: WRITE_SIZE 81MB->1.5GB/dispatch, S0 78->580us.
// STRUCTURAL FACT: TILE=128 modes (S0/WHITEN/COLOR) are register-limited to
// 2 blocks/CU regardless of LDS; r19's 64KB-dbuf config is the correct
// operating point. VGPR_Count in the CSV excludes accumulator registers --
// do not size occupancy from it.
// Config: r16 core + fused argmax + WHITEN z-pin + S0 balanced+local walk
// (grid 1232) + NS KSTEP=64 + COVP KSTEP=32.
// ---------------------------------------------------------------------------

#define CH    512
#define NPIX  4096      // 64*64
#define HPAD  66
#define PPAD  4356      // 66*66
#define MROWS 4480      // padded row count for whitened-feature matrices
#define S0W   4480      // merged S0T width (full padded grid, 128-aligned)
#define NS_ITERS 7

typedef unsigned short u16;
typedef _Float16 half8 __attribute__((ext_vector_type(8)));
typedef __attribute__((ext_vector_type(4))) float f32x4;    // MFMA C/D

__device__ __forceinline__ float f16tof(u16 h){
  union { u16 u; _Float16 f; } v; v.u = h; return (float)v.f;
}
// x ~= h + l*2^-11, with l ~ 0.5|x| (never denormal). err ~ 2^-24|x|.
__device__ __forceinline__ void split2(float x, u16& h, u16& l){
  _Float16 hf = (_Float16)x;
  float r = (x - (float)hf) * 2048.0f;
  union { u16 u; _Float16 f; } hv, lv;
  hv.f = hf; lv.f = (_Float16)r;
  h = hv.u; l = lv.u;
}
__device__ __forceinline__ void gll16(const void* g, void* l){
  __builtin_amdgcn_global_load_lds((const __attribute__((address_space(1))) unsigned*)g,
                                   (__attribute__((address_space(3))) unsigned*)l,
                                   16, 0, 0);
}
__device__ __forceinline__ f32x4 mfma_f16(half8 a, half8 b, f32x4 c){
  return __builtin_amdgcn_mfma_f32_16x16x32_f16(a, b, c, 0, 0, 0);
}

// ---------------------------------------------------------------------------
enum { M_COVP = 0, M_NST = 1, M_X3 = 2, M_WHITEN = 3, M_S0 = 4, M_COLOR = 5 };

struct GP {
  const u16 *Ah, *Al, *Bh, *Bl;
  const u16 *Eh, *El, *Fh, *Fl;   // alt A/B for M_X3 z>=4
  size_t sAz, sBz;           // per-z strides (elements)
  float* Cf;
  u16 *Ch, *Cl;
  u16 *Gh, *Gl;              // alt C for M_X3 z>=4
  size_t sCz;
  const float* scales;
  const float* meanv;
  int K;                     // row stride (elements)
  int Kit;                   // K iteration length for this launch
};

// C[m][n] = sum_k A[m][k]*B[n][k], A,B as [row][K] fp16x2 (h, l*2^11).
// 256 threads = 4 waves; TILE in {64,128}; wave computes (TILE/2)^2.
// K-loop: double-buffered LDS, single barrier per K-step of KSTEP columns.
template<int TILE, int MODE, int KSTEP = 32>
__global__ __launch_bounds__(256, 2)
void gemm_sp(GP p){
  constexpr int MF = TILE / 32;
  constexpr int SLOTS = KSTEP / 8;        // 16B slots per row
  constexpr int TSUB = KSTEP / 32;        // 32-k sub-steps per K-step
  constexpr bool SYM = (MODE == M_NST) || (MODE == M_X3);
  int z = blockIdx.z;
  int m0, n0;
  int kbase = 0;
  int za = z, zout = z;
  bool mirror = false;
  if constexpr (MODE == M_COVP){
    // XCD-pinned (matrix,k-chunk): grid 1024 1D; xcd = b%8 owns 2 pairs.
    const int b = blockIdx.x;
    const int xcd = b & 7, w = b >> 3;          // w: 0..127
    const int zc = xcd*2 + (w & 1);             // (matrix,chunk) pair 0..15
    const int tile = w >> 1;                    // 0..63
    m0 = (tile >> 3)*64; n0 = (tile & 7)*64;
    kbase = (zc & 3) * p.Kit;
    za = zc >> 2; zout = zc;
  } else if constexpr (SYM){
    int bx = blockIdx.x;
    int ty = 0;
    while((ty+1)*(ty+2)/2 <= bx) ++ty;
    int tx = bx - ty*(ty+1)/2;
    m0 = ty*64; n0 = tx*64; mirror = (tx != ty);
  } else if constexpr (MODE == M_S0){
    // 35x35 square tiles, balanced+local XCD walk: in n-group g (7 n-tiles),
    // xcd x owns m-tiles m%8 == (x+3g)%8. Per-XCD totals 154 (x=3: 147).
    const int b = blockIdx.x;                  // grid 1232 = 8*154
    const int x = b & 7;
    int rem = b >> 3;                          // 0..153
    int g = 0, R = 0, mo = 0;
    for(; g < 5; ++g){
      mo = (x + 3*g) & 7;
      R = (mo < 3) ? 5 : 4;
      if(rem < R*7) break;
      rem -= R*7;
    }
    if(g == 5) return;
    const int mi = rem / 7, ni = rem % 7;
    m0 = (mo + mi*8) * 128;
    n0 = (g*7 + ni) * 128;
  } else if constexpr (MODE == M_WHITEN){
    // XCD z-pinned: z = xcd/2; per XCD 16 m-tiles x 4 n-tiles, n innermost
    // so B(=Z, 1MB) stays L2-resident while A streams once.
    const int b = blockIdx.x;                  // grid 512 = 8*64
    const int x = b & 7, w = b >> 3;           // w: 0..63
    z = x >> 1;
    const int mt = (x & 1) + (w >> 2) * 2;     // 0..31
    m0 = mt * 128;
    n0 = (w & 3) * 128;
    za = z; zout = z;
  } else {
    m0 = blockIdx.y*TILE; n0 = blockIdx.x*TILE;
  }

  const u16 *Ah, *Al, *Bh, *Bl;
  if constexpr (MODE == M_X3){
    const size_t zb = (size_t)(z & 3) * CH * CH;
    if(z < 4){ Ah=p.Ah+zb; Al=p.Al+zb; Bh=p.Bh+zb; Bl=p.Bl+zb; }
    else     { Ah=p.Eh+zb; Al=p.El+zb; Bh=p.Fh+zb; Bl=p.Fl+zb; }
  } else {
    Ah = p.Ah + (size_t)za * p.sAz;
    Al = p.Al + (size_t)za * p.sAz;
    Bh = p.Bh + (size_t)za * p.sBz;
    Bl = p.Bl + (size_t)za * p.sBz;
  }

  const int tid = threadIdx.x, ln = tid & 63, wv = tid >> 6;
  const int wm = (wv >> 1) * (TILE/2), wn = (wv & 1) * (TILE/2);
  __shared__ __align__(16) u16 sAh[2][TILE*KSTEP], sAl[2][TILE*KSTEP];
  __shared__ __align__(16) u16 sBh[2][TILE*KSTEP], sBl[2][TILE*KSTEP];
  f32x4 acc1[MF][MF], acc2[MF][MF];
#pragma unroll
  for(int i=0;i<MF;++i)
#pragma unroll
    for(int j=0;j<MF;++j){ acc1[i][j] = (f32x4)0.0f; acc2[i][j] = (f32x4)0.0f; }
  const int K = p.K;

  auto stage = [&](int k0, int buf){
#pragma unroll
    for(int s = tid; s < TILE*SLOTS; s += 256){  // 16B slots, SLOTS per row
      const int row = s / SLOTS, pos = s % SLOTS;
      const int kc = pos ^ ((row >> 2) & (SLOTS-1));   // XOR swizzle
      const size_t ga = (size_t)(m0 + row) * K + k0 + kc*8;
      const size_t gb = (size_t)(n0 + row) * K + k0 + kc*8;
      gll16(Ah + ga, sAh[buf] + s*8);
      gll16(Al + ga, sAl[buf] + s*8);
      gll16(Bh + gb, sBh[buf] + s*8);
      gll16(Bl + gb, sBl[buf] + s*8);
    }
  };

  stage(kbase, 0);
  int cur = 0;
  for(int kk = 0; kk < p.Kit; kk += KSTEP){
    __syncthreads();                   // drains prefetch issued last iter
    if(kk + KSTEP < p.Kit) stage(kbase + kk + KSTEP, cur ^ 1);  // async prefetch
    const u16* pAh = sAh[cur]; const u16* pAl = sAl[cur];
    const u16* pBh = sBh[cur]; const u16* pBl = sBl[cur];
#pragma unroll
    for(int t = 0; t < TSUB; ++t){
      half8 ah[MF], al[MF], bh[MF], bl[MF];
#pragma unroll
      for(int i=0;i<MF;++i){
        const int ra = wm + i*16 + (ln & 15);
        const int rb = wn + i*16 + (ln & 15);
        const int pa = (t*4 + (ln >> 4)) ^ ((ra >> 2) & (SLOTS-1));
        const int pb = (t*4 + (ln >> 4)) ^ ((rb >> 2) & (SLOTS-1));
        const int ofa = ra*KSTEP + pa*8;
        const int ofb = rb*KSTEP + pb*8;
        ah[i] = *(const half8*)(pAh + ofa);
        al[i] = *(const half8*)(pAl + ofa);
        bh[i] = *(const half8*)(pBh + ofb);
        bl[i] = *(const half8*)(pBl + ofb);
      }
#pragma unroll
      for(int i=0;i<MF;++i)
#pragma unroll
        for(int j=0;j<MF;++j){
          acc1[i][j] = mfma_f16(ah[i], bh[j], acc1[i][j]);
          acc2[i][j] = mfma_f16(ah[i], bl[j], acc2[i][j]);
          acc2[i][j] = mfma_f16(al[i], bh[j], acc2[i][j]);
        }
    }
    cur ^= 1;
  }
  // epilogue: C/D layout col=lane&15, row=(lane>>4)*4+reg
  u16 *C0 = nullptr, *C1 = nullptr;
  if constexpr (MODE == M_NST){
    const size_t zb = (size_t)z * p.sCz;
    C0 = p.Ch + zb; C1 = p.Cl + zb;
  } else if constexpr (MODE == M_X3){
    const size_t zb = (size_t)(z & 3) * p.sCz;
    if(z < 4){ C0 = p.Ch + zb; C1 = p.Cl + zb; }
    else     { C0 = p.Gh + zb; C1 = p.Gl + zb; }
  }
#pragma unroll
  for(int i=0;i<MF;++i)
#pragma unroll
    for(int j=0;j<MF;++j)
#pragma unroll
      for(int r=0;r<4;++r){
        const int m = m0 + wm + i*16 + (ln >> 4)*4 + r;
        const int n = n0 + wn + j*16 + (ln & 15);
        float v = acc1[i][j][r] + acc2[i][j][r] * (1.0f/2048.0f);
        if constexpr (MODE == M_COVP){
          p.Cf[(size_t)zout * p.sCz + (size_t)m * CH + n] = v;   // raw partial
        } else if constexpr (MODE == M_NST || MODE == M_X3){
          if constexpr (MODE == M_NST) v = -0.5f*v + ((m == n) ? 1.5f : 0.0f);
          u16 h, l; split2(v, h, l);
          C0[(size_t)m*CH + n] = h; C1[(size_t)m*CH + n] = l;
          if(mirror){
            C0[(size_t)n*CH + m] = h; C1[(size_t)n*CH + m] = l;
          }
        } else if constexpr (MODE == M_WHITEN){
          v *= p.scales[z*4 + 3];                 // rsqrt(c)
          const int prow = ((m >> 6) + 1)*HPAD + (m & 63) + 1;
          u16 h, l; split2(v, h, l);
          const size_t o = (size_t)z*p.sCz + (size_t)prow*CH + n;
          p.Ch[o] = h; p.Cl[o] = l;
        } else if constexpr (MODE == M_S0){
          p.Cf[(size_t)m * S0W + n] = v;
        } else {                                  // M_COLOR
          const float sc = p.scales[(2+z)*4 + 2]; // sqrt(c)
          const float mu = p.meanv[(2+z)*CH + m];
          p.Cf[(size_t)z*p.sCz + (size_t)m*NPIX + n] = v*sc + mu;
        }
      }
}

// ------- cov reduce: sum 4 K-chunks, scale 1/4095; fused |row| sums ---------
// Block covers 256 consecutive elements = half a row -> one atomicAdd/block.
__global__ __launch_bounds__(256)
void cov_reduce_kernel(const float* __restrict__ covp, float* __restrict__ cov,
                       float* __restrict__ rowsum){
  size_t t = (size_t)blockIdx.x * 256 + threadIdx.x;   // 4*512*512
  int z = (int)(t >> 18);
  size_t e = t & 262143;
  float s = 0.f;
#pragma unroll
  for(int c = 0; c < 4; ++c) s += covp[((size_t)(z*4 + c) << 18) + e];
  s *= (1.0f / 4095.0f);
  cov[t] = s;
  __shared__ float red[256];
  red[threadIdx.x] = fabsf(s); __syncthreads();
  for(int w = 128; w > 0; w >>= 1){
    if(threadIdx.x < w) red[threadIdx.x] += red[threadIdx.x + w];
    __syncthreads();
  }
  if(threadIdx.x == 0){
    int row = (int)(e >> 9);
    atomicAdd(&rowsum[z*512 + row], red[0]);
  }
}

__global__ __launch_bounds__(256)
void scale_fin_kernel(const float* __restrict__ rowsum, float* __restrict__ scales){
  __shared__ float red[256];
  for(int z = 0; z < 4; ++z){
    float m = fmaxf(rowsum[z*512 + threadIdx.x], rowsum[z*512 + 256 + threadIdx.x]);
    red[threadIdx.x] = m; __syncthreads();
    for(int w = 128; w > 0; w >>= 1){
      if(threadIdx.x < w) red[threadIdx.x] = fmaxf(red[threadIdx.x], red[threadIdx.x + w]);
      __syncthreads();
    }
    if(threadIdx.x == 0){
      float c = red[0];
      scales[z*4+0] = c;
      scales[z*4+1] = 1.0f / c;
      scales[z*4+2] = sqrtf(c);
      scales[z*4+3] = rsqrtf(c);
    }
    __syncthreads();
  }
}

// ---------------- per-(matrix,channel) mean over 4096 pixels ----------------
__global__ __launch_bounds__(256)
void mean_kernel(const float* __restrict__ content, const float* __restrict__ style,
                 float* __restrict__ meanv){
  int mm = blockIdx.x;           // 0..2047
  int z = mm >> 9, c = mm & 511;
  const float* X = ((z < 2) ? content + (size_t)z * CH * NPIX
                            : style   + (size_t)(z - 2) * CH * NPIX) + (size_t)c * NPIX;
  float s = 0.f;
  for(int i = threadIdx.x; i < NPIX; i += 256) s += X[i];
  __shared__ float red[256];
  red[threadIdx.x] = s; __syncthreads();
  for(int w = 128; w > 0; w >>= 1){
    if(threadIdx.x < w) red[threadIdx.x] += red[threadIdx.x + w];
    __syncthreads();
  }
  if(threadIdx.x == 0) meanv[mm] = red[0] * (1.0f / NPIX);
}

// ------- center + fp16x2 split, emit both [c][pix] and [pix][c] layouts -----
__global__ __launch_bounds__(256)
void center_split_kernel(const float* __restrict__ content, const float* __restrict__ style,
                         const float* __restrict__ meanv,
                         u16* __restrict__ Xch, u16* __restrict__ Xcl,
                         u16* __restrict__ XcTh, u16* __restrict__ XcTl){
  int z = blockIdx.z;
  const float* X = (z < 2) ? content + (size_t)z * CH * NPIX
                           : style   + (size_t)(z - 2) * CH * NPIX;
  int p0 = blockIdx.x * 64, c0 = blockIdx.y * 64;
  __shared__ float T[64][65];
  int col = threadIdx.x & 63, rq = threadIdx.x >> 6;
#pragma unroll
  for(int i = 0; i < 16; ++i){
    int r = i*4 + rq;
    int c = c0 + r;
    float v = X[(size_t)c * NPIX + p0 + col] - meanv[z*CH + c];
    u16 h, l; split2(v, h, l);
    size_t o = (size_t)(z*CH + c) * NPIX + p0 + col;
    Xch[o] = h; Xcl[o] = l;
    T[col][r] = v;
  }
  __syncthreads();
#pragma unroll
  for(int i = 0; i < 16; ++i){
    int r = i*4 + rq;                 // pixel-in-tile
    float v = T[r][col];
    u16 h, l; split2(v, h, l);
    size_t o = (size_t)(z*NPIX + p0 + r) * CH + c0 + col;
    XcTh[o] = h; XcTl[o] = l;
  }
}

// ---------------- Y0 = cov/c (x2), Z0 = I (x2) ------------------------------
__global__ __launch_bounds__(256)
void ns_init_kernel(const float* __restrict__ cov, const float* __restrict__ scales,
                    u16* Yh, u16* Yl, u16* Zh, u16* Zl){
  size_t t = (size_t)blockIdx.x * 256 + threadIdx.x;   // 4*512*512
  int z = (int)(t >> 18);
  size_t e = t & 262143;
  int row = (int)(e >> 9), col = (int)(e & 511);
  float v = cov[t] * scales[z*4+1];
  u16 h, l; split2(v, h, l);
  Yh[t] = h; Yl[t] = l;
  Zh[t] = (row == col) ? (u16)0x3C00 : (u16)0;   // fp16 1.0
  Zl[t] = 0;
}

// ---------------- cn2[p'] = ||whitened style column||^2 ---------------------
__global__ __launch_bounds__(256)
void cn2_kernel(const u16* __restrict__ Wh, const u16* __restrict__ Wl,
                float* __restrict__ cn2){
  int b = blockIdx.y;
  int row = blockIdx.x * 16 + (threadIdx.x >> 4);
  int t = threadIdx.x & 15;
  float s = 0.f;
  if(row < PPAD){
    size_t base = ((size_t)(2 + b) * MROWS + row) * CH;
    for(int ch = t; ch < 64; ch += 16){
      uint4 hv = *(const uint4*)(Wh + base + ch*8);
      uint4 lv = *(const uint4*)(Wl + base + ch*8);
      const unsigned* hw = (const unsigned*)&hv;
      const unsigned* lw = (const unsigned*)&lv;
#pragma unroll
      for(int w = 0; w < 4; ++w){
        float v0 = f16tof((u16)(hw[w] & 0xFFFF)) + f16tof((u16)(lw[w] & 0xFFFF))*(1.0f/2048.0f);
        float v1 = f16tof((u16)(hw[w] >> 16))    + f16tof((u16)(lw[w] >> 16))*(1.0f/2048.0f);
        s = fmaf(v0, v0, s); s = fmaf(v1, v1, s);
      }
    }
  }
  for(int off = 8; off; off >>= 1) s += __shfl_down(s, off, 16);
  if(t == 0 && row < PPAD) cn2[b*PPAD + row] = s;
}

// ---------------- rnorm[p] = 1/(sqrt(sum of 9 taps)+1e-5) -------------------
__global__ __launch_bounds__(256)
void rnorm_kernel(const float* __restrict__ cn2, float* __restrict__ rnorm){
  int b = blockIdx.y;
  int p = blockIdx.x * 256 + threadIdx.x;   // 0..4095
  int py = p >> 6, px = p & 63;
  const float* c2 = cn2 + (size_t)b * PPAD + (size_t)py * HPAD + px;
  float s = 0.f;
#pragma unroll
  for(int i = 0; i < 3; ++i)
#pragma unroll
    for(int j = 0; j < 3; ++j) s += c2[i * HPAD + j];
  rnorm[b * 4096 + p] = 1.0f / (sqrtf(s) + 1e-5f);
}

// ---------------- per-p-chunk argmax of 9-tap stencil score (fused) ---------
// XCD-pinned p-slices; 2 q-streams per thread; result via packed u64
// atomicMax: key = (ordered_f32(score) << 32) | (0xFFFFFFFF - p).
// Exactly reproduces first-max (lowest-p) selection of a serial scan.
__device__ __forceinline__ unsigned long long score_key(float s, int p){
  unsigned u = __float_as_uint(s);
  u = (u & 0x80000000u) ? ~u : (u | 0x80000000u);
  return ((unsigned long long)u << 32) | (unsigned long long)(0xFFFFFFFFu - (unsigned)p);
}

__global__ __launch_bounds__(256)
void score_partial_kernel(const float* __restrict__ S0T, const float* __restrict__ rnorm,
                          unsigned long long* __restrict__ skey, int b){
  const int blk = blockIdx.x;                // grid 512
  const int xcd = blk & 7, w = blk >> 3;     // w: 0..63
  const int chunk = xcd*8 + (w & 7);
  const int qg = w >> 3;                     // 0..7
  const int t = threadIdx.x;
  const int q0 = qg*512 + t, q1 = q0 + 256;
  const int qc0 = (q0 >> 6)*HPAD + (q0 & 63);
  const int qc1 = (q1 >> 6)*HPAD + (q1 & 63);
  const float* rn = rnorm + b * 4096;
  float b0 = -1e30f, b1 = -1e30f; int i0 = 0, i1 = 0;
  for(int p = chunk*64; p < chunk*64 + 64; ++p){
    const size_t base = (size_t)((p >> 6)*HPAD + (p & 63)) * S0W;
    float s0 = 0.f, s1 = 0.f;
#pragma unroll
    for(int i = 0; i < 3; ++i)
#pragma unroll
      for(int j = 0; j < 3; ++j){
        const size_t d = (size_t)(i*HPAD + j) * (S0W + 1);
        s0 += S0T[base + qc0 + d];
        s1 += S0T[base + qc1 + d];
      }
    const float r = rn[p];
    s0 *= r; s1 *= r;
    if(s0 > b0){ b0 = s0; i0 = p; }
    if(s1 > b1){ b1 = s1; i1 = p; }
  }
  atomicMax(skey + (size_t)b*4096 + q0, score_key(b0, i0));
  atomicMax(skey + (size_t)b*4096 + q1, score_key(b1, i1));
}

// ---------------- gather matched patches, overlap-add, write RT x2 ----------
__global__ __launch_bounds__(256)
void gather_kernel(const u16* __restrict__ Wh, const u16* __restrict__ Wl,
                   const unsigned long long* __restrict__ skey,
                   u16* __restrict__ RTh, u16* __restrict__ RTl){
  int g = blockIdx.x * 256 + threadIdx.x;   // 2*4096*64
  int cg = g & 63;
  int pix = (g >> 6) & 4095;
  int b = g >> 18;
  int y = pix >> 6, x = pix & 63;
  const unsigned long long* kb = skey + (size_t)b * 4096;
  size_t matbase = (size_t)(2 + b) * MROWS * CH;
  float a8[8] = {0,0,0,0,0,0,0,0};
  int cnt = 0;
#pragma unroll
  for(int i = 0; i < 3; ++i){
    int qy = y + 1 - i;
    if((unsigned)qy >= 64u) continue;
#pragma unroll
    for(int j = 0; j < 3; ++j){
      int qx = x + 1 - j;
      if((unsigned)qx >= 64u) continue;
      int p = (int)(0xFFFFFFFFu - (unsigned)(kb[qy * 64 + qx] & 0xFFFFFFFFull));
      int row = ((p >> 6) + i) * HPAD + (p & 63) + j;
      size_t off = matbase + (size_t)row * CH + cg * 8;
      uint4 hv = *(const uint4*)(Wh + off);
      uint4 lv = *(const uint4*)(Wl + off);
      const unsigned* hw = (const unsigned*)&hv;
      const unsigned* lw = (const unsigned*)&lv;
#pragma unroll
      for(int w = 0; w < 4; ++w){
        a8[2*w]   += f16tof((u16)(hw[w] & 0xFFFF)) + f16tof((u16)(lw[w] & 0xFFFF))*(1.0f/2048.0f);
        a8[2*w+1] += f16tof((u16)(hw[w] >> 16))    + f16tof((u16)(lw[w] >> 16))*(1.0f/2048.0f);
      }
      ++cnt;
    }
  }
  float inv = 1.0f / (float)cnt;
  u16 oh[8], ol[8];
#pragma unroll
  for(int k = 0; k < 8; ++k){
    float v = a8[k] * inv;
    split2(v, oh[k], ol[k]);
  }
  size_t ro = ((size_t)(b * 4096 + pix)) * CH + cg * 8;
  *(uint4*)(RTh + ro) = *(const uint4*)oh;
  *(uint4*)(RTl + ro) = *(const uint4*)ol;
}

// ---------------------------------------------------------------------------
extern "C" void kernel_launch(void* const* d_in, const int* in_sizes, int n_in,
                              void* d_out, int out_size, void* d_ws, size_t ws_size,
                              hipStream_t stream){
  (void)in_sizes; (void)n_in; (void)out_size; (void)ws_size;
  const float* content = (const float*)d_in[0];
  const float* style   = (const float*)d_in[1];
  float* out = (float*)d_out;

  char* base = (char*)d_ws;
  size_t off = 0;
  auto take = [&](size_t nbytes) -> char* {
    char* p = base + off;
    off = (off + nbytes + 255) & ~(size_t)255;
    return p;
  };
  const size_t MAT = (size_t)CH*CH*2;            // 512x512 fp16 bytes
  const size_t FEAT = (size_t)CH*NPIX*2;         // 512x4096 fp16 bytes
  const size_t WMAT = (size_t)MROWS*CH*2;        // 4480x512 fp16 bytes
  const size_t S0SZ = (size_t)MROWS*S0W*4;       // 80.3 MB merged S0T

  float* meanv  = (float*)take((size_t)4*CH*sizeof(float));
  float* scales = (float*)take(256);
  float* rowsum = (float*)take((size_t)4*CH*sizeof(float));  // memset to 0
  float* cov    = (float*)take((size_t)4*CH*CH*sizeof(float));
  u16 *Yh=(u16*)take(4*MAT), *Yl=(u16*)take(4*MAT);
  u16 *Zh=(u16*)take(4*MAT), *Zl=(u16*)take(4*MAT);
  u16 *Th=(u16*)take(4*MAT), *Tl=(u16*)take(4*MAT);
  u16 *Ynh=(u16*)take(4*MAT), *Ynl=(u16*)take(4*MAT);
  u16 *Znh=(u16*)take(4*MAT), *Znl=(u16*)take(4*MAT);
  // cov K-split partials (16 MB) alias the NS region (dead at cov time):
  // Yh..Ynl are 8 contiguous 2MB arrays (256B-aligned takes).
  float* covp = (float*)Yh;
  // P1: Xc x2 (center->cov) then W x2 (post-NS -> end)
  char* P1 = take(2*(size_t)4*WMAT);
  u16 *Xch=(u16*)P1, *Xcl=(u16*)(P1+4*FEAT);
  u16 *Wh=(u16*)P1,  *Wl=(u16*)(P1+4*WMAT);
  // P0: XcT x2 (center->whiten), then merged S0T, then RT x2
  char* P0 = take(S0SZ);
  u16 *XcTh=(u16*)P0, *XcTl=(u16*)(P0+4*FEAT);
  float* S0T = (float*)P0;
  u16 *RTh=(u16*)P0, *RTl=(u16*)(P0+2*FEAT);
  float* cn2    = (float*)take((size_t)2*PPAD*sizeof(float));
  float* rnormb = (float*)take((size_t)2*4096*sizeof(float));
  unsigned long long* skey = (unsigned long long*)take((size_t)2*4096*8);

  hipMemsetAsync(rowsum, 0, (size_t)4*CH*sizeof(float), stream);
  hipMemsetAsync(skey, 0, (size_t)2*4096*8, stream);

  mean_kernel<<<2048, 256, 0, stream>>>(content, style, meanv);
  center_split_kernel<<<dim3(64, 8, 4), 256, 0, stream>>>(content, style, meanv,
                                                          Xch, Xcl, XcTh, XcTl);
  // cov partials: XCD-pinned (matrix,k-chunk), 1024 blocks 1D, KSTEP=32
  // (32KB LDS; VGPR fits 4 blocks/CU residency = the 4 blocks/CU of work)
  {
    GP g{}; g.Ah=Xch; g.Al=Xcl; g.Bh=Xch; g.Bl=Xcl;
    g.sAz = g.sBz = (size_t)CH*NPIX; g.Cf = covp; g.sCz = (size_t)CH*CH;
    g.K = NPIX; g.Kit = 1024;
    gemm_sp<64, M_COVP, 32><<<dim3(1024), 256, 0, stream>>>(g);
  }
  cov_reduce_kernel<<<4096, 256, 0, stream>>>(covp, cov, rowsum);
  scale_fin_kernel<<<1, 256, 0, stream>>>(rowsum, scales);
  ns_init_kernel<<<4096, 256, 0, stream>>>(cov, scales, Yh, Yl, Zh, Zl);

  u16 *Ach[2]={Yh,Yl}, *Bch[2]={Zh,Zl}, *An[2]={Ynh,Ynl}, *Bn[2]={Znh,Znl};
  for(int it = 0; it < NS_ITERS; ++it){
    // T = 1.5I - 0.5 Z*Y  (symmetric: 36 triangle blocks, mirrored)
    GP t{}; t.Ah=Bch[0]; t.Al=Bch[1];            // Z
    t.Bh=Ach[0]; t.Bl=Ach[1];                    // Y (symmetric)
    t.sAz = t.sBz = (size_t)CH*CH; t.Ch=Th; t.Cl=Tl; t.sCz=(size_t)CH*CH;
    t.K = CH; t.Kit = CH;
    gemm_sp<64, M_NST, 64><<<dim3(36, 1, 4), 256, 0, stream>>>(t);
    // z<4: Yn = Y*T ; z>=4: Zn = T*Z  (both symmetric, mirrored)
    GP u{}; u.Ah=Ach[0]; u.Al=Ach[1];            // Y
    u.Bh=Th; u.Bl=Tl;                            // T
    u.Eh=Th; u.El=Tl;                            // T
    u.Fh=Bch[0]; u.Fl=Bch[1];                    // Z
    u.Ch=An[0]; u.Cl=An[1];
    u.Gh=Bn[0]; u.Gl=Bn[1];
    u.sCz=(size_t)CH*CH; u.K = CH; u.Kit = CH;
    gemm_sp<64, M_X3, 64><<<dim3(36, 1, 8), 256, 0, stream>>>(u);
    for(int c = 0; c < 2; ++c){ u16* tmp=Ach[c]; Ach[c]=An[c]; An[c]=tmp;
                                tmp=Bch[c]; Bch[c]=Bn[c]; Bn[c]=tmp; }
  }

  // W (padded, zero borders) -- Xc region is dead now; Wh/Wl alias it
  hipMemsetAsync(Wh, 0, 4*WMAT, stream);
  hipMemsetAsync(Wl, 0, 4*WMAT, stream);
  // W[pix][c] = XcT * Z  (Z symmetric), scaled by rsqrt(c); XCD z-pinned 1D
  {
    GP w{}; w.Ah=XcTh; w.Al=XcTl; w.sAz=(size_t)NPIX*CH;
    w.Bh=Bch[0]; w.Bl=Bch[1]; w.sBz=(size_t)CH*CH;
    w.Ch=Wh; w.Cl=Wl; w.sCz=(size_t)MROWS*CH; w.scales=scales;
    w.K = CH; w.Kit = CH;
    gemm_sp<128, M_WHITEN, 32><<<dim3(512), 256, 0, stream>>>(w);
  }
  cn2_kernel<<<dim3(273, 2), 256, 0, stream>>>(Wh, Wl, cn2);
  rnorm_kernel<<<dim3(16, 2), 256, 0, stream>>>(cn2, rnormb);

  for(int b = 0; b < 2; ++b){
    GP s{};
    s.Ah = Wh + (size_t)(2+b)*MROWS*CH; s.Al = Wl + (size_t)(2+b)*MROWS*CH;
    s.Bh = Wh + (size_t)b*MROWS*CH;     s.Bl = Wl + (size_t)b*MROWS*CH;
    s.sAz = s.sBz = 0; s.Cf = S0T; s.sCz = 0; s.K = CH; s.Kit = CH;
    gemm_sp<128, M_S0, 32><<<dim3(1232), 256, 0, stream>>>(s);
    score_partial_kernel<<<dim3(512), 256, 0, stream>>>(S0T, rnormb, skey, b);
  }

  gather_kernel<<<2048, 256, 0, stream>>>(Wh, Wl, skey, RTh, RTl);
  // out = Ys * R * sqrt(c) + mu   (Ys symmetric)
  {
    GP c{}; c.Ah = Ach[0] + 2*(size_t)CH*CH; c.Al = Ach[1] + 2*(size_t)CH*CH;
    c.sAz = (size_t)CH*CH;
    c.Bh = RTh; c.Bl = RTl; c.sBz = (size_t)NPIX*CH;
    c.Cf = out; c.sCz = (size_t)CH*NPIX; c.scales = scales; c.meanv = meanv;
    c.K = CH; c.Kit = CH;
    gemm_sp<128, M_COLOR, 32><<<dim3(32, 4, 2), 256, 0, stream>>>(c);
  }
}